// Round 3
// baseline (170.397 us; speedup 1.0000x reference)
//
#include <hip/hip_runtime.h>
#include <math.h>

// SpiralNet bf16-MFMA v9: attack average gather LATENCY, not concurrency.
// v8 established: offered MLP (120/CU) >> HW outstanding-miss cap (~48/CU),
// so t ~ lines * L_avg. Two changes to cut L_avg:
//  1. Column-blocked half-tables + phase-major K order (CIN=64 layers):
//     h1/h2 stored as two contiguous [N x 32] tables. All 12 gathers of
//     phase 0 (cols 0-31) run before phase 1 -> random working set per
//     phase halves (12.8 -> 6.4 MB) -> XCD-L2 hit ~31% -> ~62%.
//     Line count per row unchanged (two 64B halves were already two
//     separate 64B transactions).
//  2. Cache hygiene: nontemporal epilogue stores (12.8 MB stream) and
//     nontemporal idx loads (4.8 MB one-touch) stop evicting the gather
//     table from L2. Gathers + packed-B stay cached.
// Structure otherwise identical to v8 (fenced depth-6 batches, 24 KB LDS
// chunks, 5 blocks/CU, MR=1).
// [Rounds 1-2: resubmitted unchanged — GPU broker timeouts, no data.]

typedef __bf16 bf16;
typedef bf16  bf16x4 __attribute__((ext_vector_type(4)));
typedef bf16  bf16x8 __attribute__((ext_vector_type(8)));
typedef float f32x4  __attribute__((ext_vector_type(4)));
typedef int   intx4  __attribute__((ext_vector_type(4)));

// Pack W [K][COUT] f32 into fragment-ordered bf16, PHASE-MAJOR:
// frag f = (ph*12 + s)*NT + t; element lane*8+j of frag f is
// W[k = s*CIN + ph*32 + (lane>>4)*8 + j][col = t*16 + (lane&15)].
template<int CIN, int COUT>
__device__ inline void pack_one(const float* __restrict__ W, bf16* __restrict__ BP, int e) {
    constexpr int NT = COUT / 16;
    const int f = e >> 9, r = e & 511, lane = r >> 3, j = r & 7;
    const int t = f % NT, s = (f / NT) % 12, ph = f / (NT * 12);
    const int col = t * 16 + (lane & 15);
    const int k   = s * CIN + ph * 32 + (lane >> 4) * 8 + j;
    BP[e] = (bf16)W[k * COUT + col];
}

__global__ __launch_bounds__(256)
void prep_all(const float* __restrict__ x, bf16* __restrict__ xb,
              const float* __restrict__ W0, const float* __restrict__ W1,
              const float* __restrict__ W2, bf16* __restrict__ B0,
              bf16* __restrict__ B1, bf16* __restrict__ B2, int n)
{
    const int gid = blockIdx.x * 256 + threadIdx.x;
    const int e = gid * 4;
    if (e < n * 32) {
        const f32x4 v = *reinterpret_cast<const f32x4*>(x + e);
        bf16x4 o = {(bf16)v[0], (bf16)v[1], (bf16)v[2], (bf16)v[3]};
        *reinterpret_cast<bf16x4*>(xb + e) = o;
    }
    if (gid < 384 * 64)                       pack_one<32, 64>(W0, B0, gid);
    else if (gid < 384 * 64 + 768 * 64)       pack_one<64, 64>(W1, B1, gid - 384 * 64);
    else if (gid < 384 * 64 + 768 * 64 + 768 * 32)
                                              pack_one<64, 32>(W2, B2, gid - 384 * 64 - 768 * 64);
}

// PH = 1: single input table hA (stride 32), like old CIN=32.
// PH = 2: two half tables hA (cols 0-31), hB (cols 32-63), phase-major.
// SPLITOUT: COUT=64 intermediate -> write two [n x 32] half tables.
template<int PH, int COUT, bool ELU, bool SPLITOUT, typename TOUT>
__global__ __launch_bounds__(256, 5)
void spiral_mfma(const bf16* __restrict__ hA, const bf16* __restrict__ hB,
                 const int* __restrict__ idx, const bf16* __restrict__ BP,
                 const float* __restrict__ bias,
                 TOUT* __restrict__ outA, TOUT* __restrict__ outB, int n)
{
    constexpr int NT  = COUT / 16;       // 16-col output tiles (2 or 4)
    constexpr int NCH = 2 * PH;          // chunks of 6 steps each
    constexpr int CHE = 6 * 32 * COUT;   // B elems per chunk (24 KB / 12 KB)

    __shared__ bf16 Bs[CHE];

    const int tid  = threadIdx.x;
    const int lane = tid & 63;
    const int wave = tid >> 6;           // 0..3
    const int m    = lane & 15;
    const int quad = lane >> 4;
    const int i0   = (blockIdx.x * 4 + wave) * 16;   // one 16-row tile/wave
    const bool valid = (i0 < n);

    // Gather indices (48B/row, 16B-aligned), nontemporal (one-touch stream).
    const int ir = min(i0 + m, n - 1);
    const intx4* ip = reinterpret_cast<const intx4*>(idx + (size_t)ir * 12);
    const intx4 q0 = __builtin_nontemporal_load(ip);
    const intx4 q1 = __builtin_nontemporal_load(ip + 1);
    const intx4 q2 = __builtin_nontemporal_load(ip + 2);
    const int rg[12] = {q0.x,q0.y,q0.z,q0.w, q1.x,q1.y,q1.z,q1.w, q2.x,q2.y,q2.z,q2.w};

    f32x4 acc[NT] = {};

    #pragma unroll
    for (int c = 0; c < NCH; ++c) {
        if (c) __syncthreads();          // Bs reuse: consumers done
        // Stage chunk c of packed B into LDS (contiguous 16B copies, cached).
        const bf16* src = BP + (size_t)c * CHE;
        #pragma unroll
        for (int r2 = tid; r2 < CHE / 8; r2 += 256)
            *reinterpret_cast<bf16x8*>(&Bs[r2 * 8]) =
                *reinterpret_cast<const bf16x8*>(&src[r2 * 8]);
        __syncthreads();

        const int ph = (PH == 2) ? (c >> 1) : 0;       // column phase
        const int sb = (PH == 2) ? ((c & 1) * 6) : (c * 6);  // first step
        const bf16* tab = ph ? hB : hA;

        // ---- fenced batch: 6 independent gathers, then 6*NT MFMAs ----
        bf16x8 a[6];
        #pragma unroll
        for (int sl = 0; sl < 6; ++sl)
            a[sl] = *reinterpret_cast<const bf16x8*>(
                tab + (size_t)rg[sb + sl] * 32 + quad * 8);
        __builtin_amdgcn_sched_barrier(0);   // all 6 loads issue before MFMAs
        #pragma unroll
        for (int p = 0; p < 6; ++p)
            #pragma unroll
            for (int t = 0; t < NT; ++t) {
                const bf16x8 b = *reinterpret_cast<const bf16x8*>(
                    &Bs[(p * NT + t) * 512 + lane * 8]);
                acc[t] = __builtin_amdgcn_mfma_f32_16x16x32_bf16(a[p], b, acc[t], 0, 0, 0);
            }
    }

    if (!valid) return;

    // Epilogue: D[row = quad*4+g][col = t*16+m]; nontemporal stores keep the
    // gather table resident in L2.
    #pragma unroll
    for (int t = 0; t < NT; ++t) {
        const int col = t * 16 + m;
        const float bv = bias[col];
        #pragma unroll
        for (int g = 0; g < 4; ++g) {
            const int row = i0 + quad * 4 + g;
            float v = acc[t][g] + bv;
            if (ELU) v = (v > 0.f) ? v : (__expf(v) - 1.f);
            if (SPLITOUT) {
                TOUT* o = (t < 2) ? outA : outB;
                __builtin_nontemporal_store((TOUT)v, o + (size_t)row * 32 + (t & 1) * 16 + m);
            } else {
                __builtin_nontemporal_store((TOUT)v, outA + (size_t)row * COUT + col);
            }
        }
    }
}

extern "C" void kernel_launch(void* const* d_in, const int* in_sizes, int n_in,
                              void* d_out, int out_size, void* d_ws, size_t ws_size,
                              hipStream_t stream) {
    const float* x   = (const float*)d_in[0];   // [N,32] fp32
    const int*   idx = (const int*)d_in[1];     // [N,12]
    const float* W0  = (const float*)d_in[2];   // [384,64]
    const float* b0  = (const float*)d_in[3];
    const float* W1  = (const float*)d_in[4];   // [768,64]
    const float* b1  = (const float*)d_in[5];
    const float* W2  = (const float*)d_in[6];   // [768,32]
    const float* b2  = (const float*)d_in[7];
    float* out = (float*)d_out;                 // [N,32] fp32

    const int n = in_sizes[0] / 32;             // N = 100000

    bf16* xb  = (bf16*)d_ws;                    // [n,32] (single table, PH=1)
    bf16* h1A = xb  + (size_t)n * 32;           // [n,32] cols 0-31 of h1
    bf16* h1B = h1A + (size_t)n * 32;           // [n,32] cols 32-63 of h1
    bf16* h2A = h1B + (size_t)n * 32;           // [n,32] cols 0-31 of h2
    bf16* h2B = h2A + (size_t)n * 32;           // [n,32] cols 32-63 of h2
    bf16* B0  = h2B + (size_t)n * 32;           // 12*32*64 = 24576
    bf16* B1  = B0 + 384 * 64;                  // 12*64*64 = 49152
    bf16* B2  = B1 + 768 * 64;                  // 12*64*32 = 24576

    const int prep_threads = n * 8;             // covers n*32/4 cvt + 98304 pack
    prep_all<<<(prep_threads + 255) / 256, dim3(256), 0, stream>>>(x, xb, W0, W1, W2, B0, B1, B2, n);

    const int grid = (n + 63) / 64;             // 4 waves x 16 rows per block
    spiral_mfma<1, 64, true,  true,  bf16 ><<<grid, dim3(256), 0, stream>>>(xb,  nullptr, idx, B0, b0, h1A, h1B, n);
    spiral_mfma<2, 64, true,  true,  bf16 ><<<grid, dim3(256), 0, stream>>>(h1A, h1B,     idx, B1, b1, h2A, h2B, n);
    spiral_mfma<2, 32, false, false, float><<<grid, dim3(256), 0, stream>>>(h2A, h2B,     idx, B2, b2, out, nullptr, n);
}

// Round 4
// 158.072 us; speedup vs baseline: 1.0780x; 1.0780x over previous
//
#include <hip/hip_runtime.h>
#include <math.h>

// SpiralNet bf16-MFMA v10: revert v9 (regressed 158.9 -> 170.4 us).
// Post-mortem: nontemporal stores on h1/h2 were wrong — those are
// producer->consumer gather tables (each row re-read ~12x next layer),
// not streams; nt discarded L2/L3 write-residency. nt idx loads discarded
// cross-layer reuse (idx read 3x). The half-table split gave no benefit:
// its working-set-halving mechanism needs inter-block phase lockstep,
// which doesn't exist. v10 = exact v8 structure (single tables, cached
// loads/stores, fenced depth-6 batches, 24 KB LDS chunks, 5 blocks/CU)
// + nontemporal store ONLY on the final fp32 output (true one-touch
// stream, never re-read) to keep layer-2 gather lines resident in L2.

typedef __bf16 bf16;
typedef bf16  bf16x4 __attribute__((ext_vector_type(4)));
typedef bf16  bf16x8 __attribute__((ext_vector_type(8)));
typedef float f32x4  __attribute__((ext_vector_type(4)));

// Pack W [K][COUT] f32 into fragment-ordered bf16:
// frag f = (s*CC + cc)*NT + t; element lane*8+j of frag f is
// W[k = s*CIN + cc*32 + (lane>>4)*8 + j][col = t*16 + (lane&15)].
template<int CIN, int COUT>
__device__ inline void pack_one(const float* __restrict__ W, bf16* __restrict__ BP, int e) {
    constexpr int NT = COUT / 16, CC = CIN / 32;
    const int f = e >> 9, r = e & 511, lane = r >> 3, j = r & 7;
    const int t = f % NT, cc = (f / NT) % CC, s = f / (NT * CC);
    const int col = t * 16 + (lane & 15);
    const int k   = s * CIN + cc * 32 + (lane >> 4) * 8 + j;
    BP[e] = (bf16)W[k * COUT + col];
}

__global__ __launch_bounds__(256)
void prep_all(const float* __restrict__ x, bf16* __restrict__ xb,
              const float* __restrict__ W0, const float* __restrict__ W1,
              const float* __restrict__ W2, bf16* __restrict__ B0,
              bf16* __restrict__ B1, bf16* __restrict__ B2, int n)
{
    const int gid = blockIdx.x * 256 + threadIdx.x;
    const int e = gid * 4;
    if (e < n * 32) {
        const f32x4 v = *reinterpret_cast<const f32x4*>(x + e);
        bf16x4 o = {(bf16)v[0], (bf16)v[1], (bf16)v[2], (bf16)v[3]};
        *reinterpret_cast<bf16x4*>(xb + e) = o;
    }
    if (gid < 384 * 64)                       pack_one<32, 64>(W0, B0, gid);
    else if (gid < 384 * 64 + 768 * 64)       pack_one<64, 64>(W1, B1, gid - 384 * 64);
    else if (gid < 384 * 64 + 768 * 64 + 768 * 32)
                                              pack_one<64, 32>(W2, B2, gid - 384 * 64 - 768 * 64);
}

template<int CIN, int COUT, bool ELU, bool NTS, typename TOUT>
__global__ __launch_bounds__(256, 5)
void spiral_mfma(const bf16* __restrict__ h, const int* __restrict__ idx,
                 const bf16* __restrict__ BP, const float* __restrict__ bias,
                 TOUT* __restrict__ out, int n)
{
    constexpr int CC  = CIN / 32;        // 32-k chunks per spiral step (1 or 2)
    constexpr int NT  = COUT / 16;       // 16-col output tiles (2 or 4)
    constexpr int PS  = CIN * COUT;      // B elems per spiral step
    constexpr int SC  = 6 / CC;          // steps/chunk -> batch depth SC*CC = 6
    constexpr int NCH = 12 / SC;         // chunks per layer (2 or 4)
    constexpr int PL  = 6;               // fenced gathers per chunk per wave

    __shared__ bf16 Bs[SC * PS];         // 24 KB (L0/L1), 12 KB (L2)

    const int tid  = threadIdx.x;
    const int lane = tid & 63;
    const int wave = tid >> 6;           // 0..3
    const int m    = lane & 15;
    const int quad = lane >> 4;
    const int i0   = (blockIdx.x * 4 + wave) * 16;   // MR=1: one 16-row tile
    const bool valid = (i0 < n);                     // n%16==0: all-or-none

    // Gather indices (48B/row, 16B-aligned), clamped for tail waves. Cached:
    // idx is re-read by all three layers.
    const int ir = min(i0 + m, n - 1);
    const int4* ip = reinterpret_cast<const int4*>(idx + (size_t)ir * 12);
    const int4 q0 = ip[0], q1 = ip[1], q2 = ip[2];
    const int rg[12] = {q0.x,q0.y,q0.z,q0.w, q1.x,q1.y,q1.z,q1.w, q2.x,q2.y,q2.z,q2.w};

    f32x4 acc[NT] = {};

    #pragma unroll
    for (int c = 0; c < NCH; ++c) {
        if (c) __syncthreads();          // Bs reuse: consumers done
        // Stage chunk c of packed B into LDS (contiguous 16B copies).
        const bf16* src = BP + (size_t)c * SC * PS;
        #pragma unroll
        for (int r2 = tid; r2 < SC * PS / 8; r2 += 256)
            *reinterpret_cast<bf16x8*>(&Bs[r2 * 8]) =
                *reinterpret_cast<const bf16x8*>(&src[r2 * 8]);
        __syncthreads();

        // ---- fenced batch: 6 independent gathers, then 6*NT MFMAs ----
        bf16x8 a[PL];
        #pragma unroll
        for (int sl = 0; sl < SC; ++sl)
            #pragma unroll
            for (int cc = 0; cc < CC; ++cc)
                a[sl * CC + cc] = *reinterpret_cast<const bf16x8*>(
                    h + (size_t)rg[c * SC + sl] * CIN + cc * 32 + quad * 8);
        __builtin_amdgcn_sched_barrier(0);   // all 6 loads issue before MFMAs
        #pragma unroll
        for (int p = 0; p < PL; ++p)
            #pragma unroll
            for (int t = 0; t < NT; ++t) {
                const bf16x8 b = *reinterpret_cast<const bf16x8*>(
                    &Bs[(p * NT + t) * 512 + lane * 8]);
                acc[t] = __builtin_amdgcn_mfma_f32_16x16x32_bf16(a[p], b, acc[t], 0, 0, 0);
            }
    }

    if (!valid) return;

    // Epilogue: D[row = quad*4+g][col = t*16+m]; n%16==0 -> no row guards.
    // Intermediate layers store CACHED (next layer gathers these rows);
    // final layer stores nontemporal (pure one-touch stream).
    #pragma unroll
    for (int t = 0; t < NT; ++t) {
        const int col = t * 16 + m;
        const float bv = bias[col];
        #pragma unroll
        for (int g = 0; g < 4; ++g) {
            const int row = i0 + quad * 4 + g;
            float v = acc[t][g] + bv;
            if (ELU) v = (v > 0.f) ? v : (__expf(v) - 1.f);
            if (NTS) __builtin_nontemporal_store((TOUT)v, out + (size_t)row * COUT + col);
            else     out[(size_t)row * COUT + col] = (TOUT)v;
        }
    }
}

extern "C" void kernel_launch(void* const* d_in, const int* in_sizes, int n_in,
                              void* d_out, int out_size, void* d_ws, size_t ws_size,
                              hipStream_t stream) {
    const float* x   = (const float*)d_in[0];   // [N,32] fp32
    const int*   idx = (const int*)d_in[1];     // [N,12]
    const float* W0  = (const float*)d_in[2];   // [384,64]
    const float* b0  = (const float*)d_in[3];
    const float* W1  = (const float*)d_in[4];   // [768,64]
    const float* b1  = (const float*)d_in[5];
    const float* W2  = (const float*)d_in[6];   // [768,32]
    const float* b2  = (const float*)d_in[7];
    float* out = (float*)d_out;                 // [N,32] fp32

    const int n = in_sizes[0] / 32;             // N = 100000

    bf16* xb = (bf16*)d_ws;                     // [n,32]
    bf16* h1 = xb + (size_t)n * 32;             // [n,64]
    bf16* h2 = h1 + (size_t)n * 64;             // [n,64]
    bf16* B0 = h2 + (size_t)n * 64;             // 384*64
    bf16* B1 = B0 + 384 * 64;                   // 768*64
    bf16* B2 = B1 + 768 * 64;                   // 768*32

    const int prep_threads = n * 8;             // covers n*32/4 cvt + 98304 pack
    prep_all<<<(prep_threads + 255) / 256, dim3(256), 0, stream>>>(x, xb, W0, W1, W2, B0, B1, B2, n);

    const int grid = (n + 63) / 64;             // 4 waves x 16 rows per block
    spiral_mfma<32, 64, true,  false, bf16 ><<<grid, dim3(256), 0, stream>>>(xb, idx, B0, b0, h1,  n);
    spiral_mfma<64, 64, true,  false, bf16 ><<<grid, dim3(256), 0, stream>>>(h1, idx, B1, b1, h2,  n);
    spiral_mfma<64, 32, false, true,  float><<<grid, dim3(256), 0, stream>>>(h2, idx, B2, b2, out, n);
}